// Round 4
// baseline (454.261 us; speedup 1.0000x reference)
//
#include <hip/hip_runtime.h>

// Problem constants
#define BB   128   // batch
#define CI   64    // in channels
#define HH   32
#define WW   32
#define CO   128   // out channels
#define IF   576   // CI*9
#define OW   32    // conv out w
#define XH   34    // haloed H
#define XW   34    // haloed W
// x' layout: [XH][XW][CI][BB] bf16(ushort);  (h',w',c,b) with h'=h+1 halo
#define XP_CB    (CI*BB)              // 8192
#define XP_ELEMS ((size_t)XH*XW*CI*BB)  // 9,469,952
#define BKC  64    // K-chunk = one full 3x3 tap (64 channels)
#define NCH  36    // 4 locations * 9 taps
#define LDK  72    // padded LDS row: 144B = 9*16B (odd 16B multiple -> b128-clean)
#define COB  64    // per-block c_out tile (CO split across 2 blocks)

using short8 = __attribute__((ext_vector_type(8))) short;
using f32x4  = __attribute__((ext_vector_type(4))) float;

__device__ __forceinline__ unsigned short f2bf(float f) {
  union { float f; unsigned int u; } v; v.f = f;
  unsigned int u = v.u;
  u = (u + 0x7FFFu + ((u >> 16) & 1u)) >> 16;   // RNE; inputs are finite
  return (unsigned short)u;
}

// HW packed fp32->bf16 (RNE), no builtin on gfx950 -> inline asm
__device__ __forceinline__ unsigned int cvt_pk_bf16(float lo, float hi) {
  unsigned int r;
  asm("v_cvt_pk_bf16_f32 %0, %1, %2" : "=v"(r) : "v"(lo), "v"(hi));
  return r;
}

// ---- pass 1: x (B,C,H,W) fp32 -> x' (H+2,W+2,C,B) bf16; halo zeroed by
// the first 132 blocks (replaces the 19 MB memset with 2.2 MB of writes) ----
__global__ __launch_bounds__(256) void transpose_x(
    const float* __restrict__ x, unsigned short* __restrict__ xp) {
  const int c = blockIdx.x >> 5;   // 0..63
  const int h = blockIdx.x & 31;   // 0..31
  __shared__ __align__(16) unsigned short tile[32][136]; // 272B row: 16B-mult
  const int t = threadIdx.x;
  const int w = t & 31, b0 = t >> 5;         // b0 0..7
#pragma unroll
  for (int p = 0; p < 16; ++p) {
    int b = b0 + p * 8;
    float v = x[(((size_t)b * CI + c) * HH + h) * WW + w];
    tile[w][b] = f2bf(v);
  }
  __syncthreads();
  const int w2 = t >> 3;                 // 0..31
  const int bb = (t & 7) * 16;           // 0..112
  const unsigned short* src = &tile[w2][bb];
  unsigned short* dst = xp + ((size_t)(h + 1) * XW + (w2 + 1)) * XP_CB + c * BB + bb;
  *(uint4*)(dst)     = *(const uint4*)(src);
  *(uint4*)(dst + 8) = *(const uint4*)(src + 8);

  // halo zero: 132 spans of 8192 ushorts (16 KB each)
  if (blockIdx.x < 132) {
    int s = blockIdx.x, hh, wh;
    if (s < 34)      { hh = 0;  wh = s; }
    else if (s < 68) { hh = 33; wh = s - 34; }
    else             { int k = s - 68; hh = 1 + (k >> 1); wh = (k & 1) * 33; }
    uint4 z; z.x = z.y = z.z = z.w = 0u;
    uint4* p = (uint4*)(xp + ((size_t)hh * XW + wh) * XP_CB) + t;
#pragma unroll
    for (int q = 0; q < 4; ++q) p[q * 256] = z;
  }
}

// ---- pass 2: per-pooled-cell GEMMs + bias + relu + maxpool ----
// K-chunk = one full 3x3 tap (BKC=64). Pipeline: 2-slot prefetch age with 2
// register sets (slot n: compute n -> writeLds n+1 (set S) -> issue n+3 into
// the just-freed set S). Loads are consumed 2 barriers after issue, so the
// writeLds vmcnt is a counted wait (batch n+2 still in flight, never 0) and
// the HBM latency tail is off the critical path.
__global__ __launch_bounds__(512, 4) void local_gemm_pool(
    const float* __restrict__ Wt, const float* __restrict__ bias,
    const unsigned short* __restrict__ xp, float* __restrict__ out) {
  __shared__ __align__(16) unsigned short Asl[2][BB][LDK];   // 36.9 KB
  __shared__ __align__(16) unsigned short Bsl[2][COB][LDK];  // 18.4 KB

  const int tid  = threadIdx.x;
  const int lane = tid & 63;
  const int wave = tid >> 6;   // 0..7

  // XCD swizzle: blockIdx%8 = XCD; all pw and both coh of a ph-row on one XCD
  // so output 64B lines merge in that XCD's L2 and the coh pair shares xp
  // (per-XCD xp footprint ~3.3 MB < 4 MB L2).
  const int bidx = blockIdx.x;
  const int x8 = bidx & 7, j = bidx >> 3;       // j 0..63
  const int coh = j & 1;
  const int pw  = (j >> 1) & 15;
  const int ph  = 2 * x8 + (j >> 5);
  const int co0 = coh * COB;

  // staging ids
  const int sa = tid & 127;      // A: batch lane (256B coalesced)
  const int ka = tid >> 7;       // 0..3 : 16-channel group
  const int sb = tid & 63;       // B: c_out lane (256B coalesced)
  const int kb = tid >> 6;       // 0..7 : 8-channel group (wave uniform)

  // compute ids (mfma 16x16x32 layouts, HW-verified)
  const int r16 = lane & 15;
  const int q8  = (lane >> 4) * 8;
  const int m0  = (wave >> 2) * 64;   // batch tile: 2 x 64
  const int n0  = (wave & 3) * 16;    // c_out tile: 4 x 16

  f32x4 acc[4] = {};
  f32x4 rmx[4] = {};   // relu => max >= 0, so 0-init is exact

  float          breg0[8], breg1[8];
  unsigned short areg0[16], areg1[16];

  auto issue = [&](int it, float* br, unsigned short* ar) {
    const int loc = it / 9, kc = it % 9;          // kc = 3x3 tap index
    const int di = kc / 3, dj = kc % 3;
    const int oh = 2 * ph + (loc >> 1), ow = 2 * pw + (loc & 1);
    const int l  = oh * OW + ow;
    // weight rows f = (kb*8 + i)*9 + kc, contiguous 256B along CO
    const float* wp = Wt + ((size_t)l * IF + (size_t)(kb * 8) * 9 + kc) * CO
                         + co0 + sb;
#pragma unroll
    for (int i = 0; i < 8; ++i) br[i] = wp[(size_t)i * 9 * CO];
    // A: haloed pixel (oh+di, ow+dj), channels ka*16..+16, batch lane sa
    const unsigned short* ap = xp + ((size_t)(oh + di) * XW + (ow + dj)) * XP_CB
                                  + (ka * 16) * BB + sa;
#pragma unroll
    for (int i = 0; i < 16; ++i) ar[i] = ap[i * BB];  // 256B stride, offset-folded
  };

  auto writeLds = [&](int it, const float* br, const unsigned short* ar) {
    const int bufI = it & 1;
    uint4 vb;
    vb.x = cvt_pk_bf16(br[0], br[1]);
    vb.y = cvt_pk_bf16(br[2], br[3]);
    vb.z = cvt_pk_bf16(br[4], br[5]);
    vb.w = cvt_pk_bf16(br[6], br[7]);
    *(uint4*)&Bsl[bufI][sb][kb * 8] = vb;    // b128, 16B-aligned
#pragma unroll
    for (int p = 0; p < 2; ++p) {
      short8 va;
#pragma unroll
      for (int i = 0; i < 8; ++i) va[i] = (short)ar[p * 8 + i];
      *(short8*)&Asl[bufI][sa][ka * 16 + p * 8] = va;   // b128, 16B-aligned
    }
  };

  auto computeChunk = [&](int it) {
    const int bufI = it & 1;
#pragma unroll
    for (int h = 0; h < 2; ++h) {            // two K=32 halves of the 64-chunk
      const int col = h * 32 + q8;
      short8 af[4], bf;
#pragma unroll
      for (int tm = 0; tm < 4; ++tm)
        af[tm] = *(const short8*)&Asl[bufI][m0 + tm * 16 + r16][col];
      bf = *(const short8*)&Bsl[bufI][n0 + r16][col];
#pragma unroll
      for (int tm = 0; tm < 4; ++tm)
        acc[tm] = __builtin_amdgcn_mfma_f32_16x16x32_bf16(af[tm], bf, acc[tm], 0, 0, 0);
    }
  };

  auto finishLoc = [&](int loc) {
    const int oh = 2 * ph + (loc >> 1), ow = 2 * pw + (loc & 1);
    const int l  = oh * OW + ow;
    const float bv = bias[l * CO + co0 + n0 + r16];
#pragma unroll
    for (int tm = 0; tm < 4; ++tm)
#pragma unroll
      for (int e = 0; e < 4; ++e) {
        float v = acc[tm][e] + bv;
        v = v > 0.f ? v : 0.f;
        rmx[tm][e] = fmaxf(rmx[tm][e], v);
        acc[tm][e] = 0.f;
      }
  };

  // prologue: fill chunks 0..2; set0 freed by writeLds(0) then refilled with 2
  issue(0, breg0, areg0);
  issue(1, breg1, areg1);
  writeLds(0, breg0, areg0);   // one prologue vmcnt stall
  issue(2, breg0, areg0);
  __syncthreads();             // buf0 ready

  for (int it2 = 0; it2 < NCH; it2 += 2) {
    // even slot n: compute n; writeLds n+1 (set1); issue n+3 (set1)
    computeChunk(it2);
    writeLds(it2 + 1, breg1, areg1);            // it2+1 <= NCH-1 always
    if (it2 + 3 < NCH) issue(it2 + 3, breg1, areg1);
    if (it2 % 9 == 8) finishLoc(it2 / 9);       // locs 0,2 end on even its (8,26)
    __syncthreads();
    // odd slot
    const int ito = it2 + 1;
    computeChunk(ito);
    if (ito + 1 < NCH) writeLds(ito + 1, breg0, areg0);
    if (ito + 3 < NCH) issue(ito + 3, breg0, areg0);
    if (ito % 9 == 8) finishLoc(ito / 9);       // locs 1,3 end on odd its (17,35)
    __syncthreads();
  }

  // store pooled tile; C/D: col=lane&15, row=(lane>>4)*4+e
  float* op = out + (ph * 16 + pw);
  const int col = co0 + n0 + r16;             // c_out
#pragma unroll
  for (int tm = 0; tm < 4; ++tm)
#pragma unroll
    for (int e = 0; e < 4; ++e) {
      const int row = m0 + tm * 16 + (lane >> 4) * 4 + e;  // batch
      op[((size_t)row * CO + col) * 256] = rmx[tm][e];
    }
}

extern "C" void kernel_launch(void* const* d_in, const int* in_sizes, int n_in,
                              void* d_out, int out_size, void* d_ws, size_t ws_size,
                              hipStream_t stream) {
  (void)in_sizes; (void)n_in; (void)out_size; (void)ws_size;
  const float* x  = (const float*)d_in[0];
  const float* w  = (const float*)d_in[1];
  const float* bs = (const float*)d_in[2];
  float* out = (float*)d_out;
  unsigned short* xp = (unsigned short*)d_ws;   // needs 18.94 MB scratch

  transpose_x<<<dim3(CI * HH), dim3(256), 0, stream>>>(x, xp);
  local_gemm_pool<<<dim3(512), dim3(512), 0, stream>>>(w, bs, xp, out);
}

// Round 5
// 454.043 us; speedup vs baseline: 1.0005x; 1.0005x over previous
//
#include <hip/hip_runtime.h>

// Problem constants
#define BB   128   // batch
#define CI   64    // in channels
#define HH   32
#define WW   32
#define CO   128   // out channels
#define IF   576   // CI*9
#define OW   32    // conv out w
#define XH   34    // haloed H
#define XW   34    // haloed W
// x' layout: [XH][XW][CI][BB] bf16(ushort);  (h',w',c,b) with h'=h+1 halo
#define XP_CB    (CI*BB)              // 8192
#define XP_ELEMS ((size_t)XH*XW*CI*BB)  // 9,469,952
#define BKC  64    // K-chunk = one full 3x3 tap (64 channels)
#define NCH  36    // 4 locations * 9 taps
#define LDK  72    // padded LDS row: 144B = 9*16B (odd 16B multiple -> b128-clean)
#define COB  64    // per-block c_out tile (CO split across 2 blocks)

// Non-draining barrier: ds_write visibility needs lgkmcnt(0), but vmcnt is
// deliberately NOT drained -- __syncthreads() lowers to s_waitcnt vmcnt(0)
// before s_barrier (m97 asm evidence), which kills cross-slot load pipelining.
// Compiler still auto-inserts counted vmcnt(N) before each breg/areg use.
#define BAR() asm volatile("s_waitcnt lgkmcnt(0)\n\ts_barrier" ::: "memory")

using short8 = __attribute__((ext_vector_type(8))) short;
using f32x4  = __attribute__((ext_vector_type(4))) float;

__device__ __forceinline__ unsigned short f2bf(float f) {
  union { float f; unsigned int u; } v; v.f = f;
  unsigned int u = v.u;
  u = (u + 0x7FFFu + ((u >> 16) & 1u)) >> 16;   // RNE; inputs are finite
  return (unsigned short)u;
}

// HW packed fp32->bf16 (RNE), no builtin on gfx950 -> inline asm
__device__ __forceinline__ unsigned int cvt_pk_bf16(float lo, float hi) {
  unsigned int r;
  asm("v_cvt_pk_bf16_f32 %0, %1, %2" : "=v"(r) : "v"(lo), "v"(hi));
  return r;
}

// ---- pass 1: x (B,C,H,W) fp32 -> x' (H+2,W+2,C,B) bf16; halo zeroed by
// the first 132 blocks (replaces the 19 MB memset with 2.2 MB of writes) ----
__global__ __launch_bounds__(256) void transpose_x(
    const float* __restrict__ x, unsigned short* __restrict__ xp) {
  const int c = blockIdx.x >> 5;   // 0..63
  const int h = blockIdx.x & 31;   // 0..31
  __shared__ __align__(16) unsigned short tile[32][136]; // 272B row: 16B-mult
  const int t = threadIdx.x;
  const int w = t & 31, b0 = t >> 5;         // b0 0..7
#pragma unroll
  for (int p = 0; p < 16; ++p) {
    int b = b0 + p * 8;
    float v = x[(((size_t)b * CI + c) * HH + h) * WW + w];
    tile[w][b] = f2bf(v);
  }
  __syncthreads();
  const int w2 = t >> 3;                 // 0..31
  const int bb = (t & 7) * 16;           // 0..112
  const unsigned short* src = &tile[w2][bb];
  unsigned short* dst = xp + ((size_t)(h + 1) * XW + (w2 + 1)) * XP_CB + c * BB + bb;
  *(uint4*)(dst)     = *(const uint4*)(src);
  *(uint4*)(dst + 8) = *(const uint4*)(src + 8);

  // halo zero: 132 spans of 8192 ushorts (16 KB each)
  if (blockIdx.x < 132) {
    int s = blockIdx.x, hh, wh;
    if (s < 34)      { hh = 0;  wh = s; }
    else if (s < 68) { hh = 33; wh = s - 34; }
    else             { int k = s - 68; hh = 1 + (k >> 1); wh = (k & 1) * 33; }
    uint4 z; z.x = z.y = z.z = z.w = 0u;
    uint4* p = (uint4*)(xp + ((size_t)hh * XW + wh) * XP_CB) + t;
#pragma unroll
    for (int q = 0; q < 4; ++q) p[q * 256] = z;
  }
}

// ---- pass 2: per-pooled-cell GEMMs + bias + relu + maxpool ----
// K-chunk = one full 3x3 tap (BKC=64). Pipeline: 2-slot prefetch age with 2
// register sets (slot n: compute n -> writeLds n+1 (set S) -> issue n+3 into
// the just-freed set S). Raw non-draining barriers (BAR) let the issued loads
// stay in flight across slots; the compiler's counted vmcnt before each
// breg/areg use is the only VMEM wait -- never vmcnt(0) in the main loop.
__global__ __launch_bounds__(512, 4) void local_gemm_pool(
    const float* __restrict__ Wt, const float* __restrict__ bias,
    const unsigned short* __restrict__ xp, float* __restrict__ out) {
  __shared__ __align__(16) unsigned short Asl[2][BB][LDK];   // 36.9 KB
  __shared__ __align__(16) unsigned short Bsl[2][COB][LDK];  // 18.4 KB

  const int tid  = threadIdx.x;
  const int lane = tid & 63;
  const int wave = tid >> 6;   // 0..7

  // XCD swizzle: blockIdx%8 = XCD; all pw and both coh of a ph-row on one XCD
  // so output 64B lines merge in that XCD's L2 and the coh pair shares xp
  // (per-XCD xp footprint ~3.3 MB < 4 MB L2).
  const int bidx = blockIdx.x;
  const int x8 = bidx & 7, j = bidx >> 3;       // j 0..63
  const int coh = j & 1;
  const int pw  = (j >> 1) & 15;
  const int ph  = 2 * x8 + (j >> 5);
  const int co0 = coh * COB;

  // staging ids
  const int sa = tid & 127;      // A: batch lane (256B coalesced)
  const int ka = tid >> 7;       // 0..3 : 16-channel group
  const int sb = tid & 63;       // B: c_out lane (256B coalesced)
  const int kb = tid >> 6;       // 0..7 : 8-channel group (wave uniform)

  // compute ids (mfma 16x16x32 layouts, HW-verified)
  const int r16 = lane & 15;
  const int q8  = (lane >> 4) * 8;
  const int m0  = (wave >> 2) * 64;   // batch tile: 2 x 64
  const int n0  = (wave & 3) * 16;    // c_out tile: 4 x 16

  f32x4 acc[4] = {};
  f32x4 rmx[4] = {};   // relu => max >= 0, so 0-init is exact

  float          breg0[8], breg1[8];
  unsigned short areg0[16], areg1[16];

  auto issue = [&](int it, float* br, unsigned short* ar) {
    const int loc = it / 9, kc = it % 9;          // kc = 3x3 tap index
    const int di = kc / 3, dj = kc % 3;
    const int oh = 2 * ph + (loc >> 1), ow = 2 * pw + (loc & 1);
    const int l  = oh * OW + ow;
    // weight rows f = (kb*8 + i)*9 + kc, contiguous 256B along CO
    const float* wp = Wt + ((size_t)l * IF + (size_t)(kb * 8) * 9 + kc) * CO
                         + co0 + sb;
#pragma unroll
    for (int i = 0; i < 8; ++i) br[i] = wp[(size_t)i * 9 * CO];
    // A: haloed pixel (oh+di, ow+dj), channels ka*16..+16, batch lane sa
    const unsigned short* ap = xp + ((size_t)(oh + di) * XW + (ow + dj)) * XP_CB
                                  + (ka * 16) * BB + sa;
#pragma unroll
    for (int i = 0; i < 16; ++i) ar[i] = ap[i * BB];  // 256B stride, offset-folded
  };

  auto writeLds = [&](int it, const float* br, const unsigned short* ar) {
    const int bufI = it & 1;
    uint4 vb;
    vb.x = cvt_pk_bf16(br[0], br[1]);
    vb.y = cvt_pk_bf16(br[2], br[3]);
    vb.z = cvt_pk_bf16(br[4], br[5]);
    vb.w = cvt_pk_bf16(br[6], br[7]);
    *(uint4*)&Bsl[bufI][sb][kb * 8] = vb;    // b128, 16B-aligned
#pragma unroll
    for (int p = 0; p < 2; ++p) {
      short8 va;
#pragma unroll
      for (int i = 0; i < 8; ++i) va[i] = (short)ar[p * 8 + i];
      *(short8*)&Asl[bufI][sa][ka * 16 + p * 8] = va;   // b128, 16B-aligned
    }
  };

  auto computeChunk = [&](int it) {
    const int bufI = it & 1;
#pragma unroll
    for (int h = 0; h < 2; ++h) {            // two K=32 halves of the 64-chunk
      const int col = h * 32 + q8;
      short8 af[4], bf;
#pragma unroll
      for (int tm = 0; tm < 4; ++tm)
        af[tm] = *(const short8*)&Asl[bufI][m0 + tm * 16 + r16][col];
      bf = *(const short8*)&Bsl[bufI][n0 + r16][col];
#pragma unroll
      for (int tm = 0; tm < 4; ++tm)
        acc[tm] = __builtin_amdgcn_mfma_f32_16x16x32_bf16(af[tm], bf, acc[tm], 0, 0, 0);
    }
  };

  auto finishLoc = [&](int loc) {
    const int oh = 2 * ph + (loc >> 1), ow = 2 * pw + (loc & 1);
    const int l  = oh * OW + ow;
    const float bv = bias[l * CO + co0 + n0 + r16];
#pragma unroll
    for (int tm = 0; tm < 4; ++tm)
#pragma unroll
      for (int e = 0; e < 4; ++e) {
        float v = acc[tm][e] + bv;
        v = v > 0.f ? v : 0.f;
        rmx[tm][e] = fmaxf(rmx[tm][e], v);
        acc[tm][e] = 0.f;
      }
  };

  // prologue: fill chunks 0..2; set0 freed by writeLds(0) then refilled with 2
  issue(0, breg0, areg0);
  issue(1, breg1, areg1);
  writeLds(0, breg0, areg0);   // compiler-counted vmcnt wait (batch 1 in flight)
  issue(2, breg0, areg0);
  BAR();                       // buf0 ready; batches 1,2 still in flight

  for (int it2 = 0; it2 < NCH; it2 += 2) {
    // even slot n: compute n; writeLds n+1 (set1); issue n+3 (set1)
    computeChunk(it2);
    writeLds(it2 + 1, breg1, areg1);            // it2+1 <= NCH-1 always
    if (it2 + 3 < NCH) issue(it2 + 3, breg1, areg1);
    if (it2 % 9 == 8) finishLoc(it2 / 9);       // locs 0,2 end on even its (8,26)
    BAR();
    // odd slot
    const int ito = it2 + 1;
    computeChunk(ito);
    if (ito + 1 < NCH) writeLds(ito + 1, breg0, areg0);
    if (ito + 3 < NCH) issue(ito + 3, breg0, areg0);
    if (ito % 9 == 8) finishLoc(ito / 9);       // locs 1,3 end on odd its (17,35)
    BAR();
  }

  // store pooled tile; C/D: col=lane&15, row=(lane>>4)*4+e
  float* op = out + (ph * 16 + pw);
  const int col = co0 + n0 + r16;             // c_out
#pragma unroll
  for (int tm = 0; tm < 4; ++tm)
#pragma unroll
    for (int e = 0; e < 4; ++e) {
      const int row = m0 + tm * 16 + (lane >> 4) * 4 + e;  // batch
      op[((size_t)row * CO + col) * 256] = rmx[tm][e];
    }
}

extern "C" void kernel_launch(void* const* d_in, const int* in_sizes, int n_in,
                              void* d_out, int out_size, void* d_ws, size_t ws_size,
                              hipStream_t stream) {
  (void)in_sizes; (void)n_in; (void)out_size; (void)ws_size;
  const float* x  = (const float*)d_in[0];
  const float* w  = (const float*)d_in[1];
  const float* bs = (const float*)d_in[2];
  float* out = (float*)d_out;
  unsigned short* xp = (unsigned short*)d_ws;   // needs 18.94 MB scratch

  transpose_x<<<dim3(CI * HH), dim3(256), 0, stream>>>(x, xp);
  local_gemm_pool<<<dim3(512), dim3(512), 0, stream>>>(w, bs, xp, out);
}